// Round 5
// baseline (6662.213 us; speedup 1.0000x reference)
//
#include <hip/hip_runtime.h>
#include <cstdint>
#include <cstddef>

#define Hn 256
#define Sn 2048
#define Bn 128
#define NT 768

typedef _Float16 half2_t __attribute__((ext_vector_type(2)));

__device__ __forceinline__ float fdot2_(half2_t a, half2_t b, float c){
#if __has_builtin(__builtin_amdgcn_fdot2)
  return __builtin_amdgcn_fdot2(a, b, c, false);
#else
  float d;
  asm volatile("v_dot2_f32_f16 %0, %1, %2, %3" : "=v"(d) : "v"(a), "v"(b), "v"(c));
  return d;
#endif
}

__device__ __forceinline__ float rfl_(float v){
  return __builtin_bit_cast(float, __builtin_amdgcn_readfirstlane(__builtin_bit_cast(int, v)));
}

__device__ __forceinline__ float sigmoid_(float v){ return 1.0f/(1.0f+__expf(-v)); }
__device__ __forceinline__ float tanh_(float v){
  float e = __expf(-2.0f*__builtin_fabsf(v));
  float r = (1.0f-e)/(1.0f+e);
  return __builtin_copysignf(r, v);
}

// One workgroup (768 thr = 12 waves, 1 WG/CU) per batch element.
// Thread t owns full w_hh row t: 128 f16-pair VGPRs, register-resident.
// amdgpu_num_vgpr(168) pins the allocation directly (advisory occupancy
// hints were ignored in rounds 2-4: allocator chose 64 VGPRs + full scratch
// spill of the weight array every time).
__global__ void
__attribute__((amdgpu_flat_work_group_size(NT, NT),
               amdgpu_waves_per_eu(3, 3),
               amdgpu_num_vgpr(168)))
bio_rnn(const float* __restrict__ x,
        const float* __restrict__ w_ih, const float* __restrict__ w_hh,
        const float* __restrict__ b_ih, const float* __restrict__ b_hh,
        const float* __restrict__ w_gain, const float* __restrict__ b_gain,
        const float* __restrict__ w_bias, const float* __restrict__ b_bias,
        const float* __restrict__ w_reflex, const float* __restrict__ b_reflex,
        const float* __restrict__ w_policy, const float* __restrict__ b_policy,
        const float* __restrict__ w_motor, const float* __restrict__ b_motor,
        float* __restrict__ y_out, float* __restrict__ router)
{
  const int b = blockIdx.x;
  const int t = threadIdx.x;

  __shared__ __align__(16) half2_t hpk[Hn/2];   // h packed f16 (256 B)
  __shared__ float A[NT];                        // gh(+gi) pre-activations
  __shared__ float GIN[Hn];                      // gi for n-rows
  __shared__ float REDp[4][8];                   // gain/bias head wave-partials
  __shared__ float REDq[4][4];                   // policy/motor head wave-partials
  __shared__ float HW[13][Hn];                   // head weights
  __shared__ float SB[10];                       // block-uniform head biases

  // ---- register-cache w_hh row t as 128 f16 pairs ----
  half2_t w[128];
  {
    const float* wr = w_hh + (size_t)t * Hn;
    #pragma unroll
    for (int k = 0; k < 128; k++){
      half2_t v; v.x = (_Float16)wr[2*k]; v.y = (_Float16)wr[2*k+1];
      w[k] = v;
    }
  }
  // w_ih row t as 3 f16 pairs
  half2_t wi0, wi1, wi2;
  {
    const float* wr = w_ih + (size_t)t * 6;
    wi0.x=(_Float16)wr[0]; wi0.y=(_Float16)wr[1];
    wi1.x=(_Float16)wr[2]; wi1.y=(_Float16)wr[3];
    wi2.x=(_Float16)wr[4]; wi2.y=(_Float16)wr[5];
  }
  const float bias_h = b_hh[t];   // folded into gh accumulator
  const float bias_i = b_ih[t];   // folded into gi

  if (t < Hn){
    HW[0][t] = w_gain[t];        HW[1][t]  = w_gain[Hn + t];
    HW[2][t] = w_bias[t];        HW[3][t]  = w_bias[Hn + t];
    HW[4][t] = w_bias[2*Hn + t]; HW[5][t]  = w_bias[3*Hn + t];
    HW[6][t] = w_reflex[2*t];    HW[7][t]  = w_reflex[2*t + 1];
    HW[8][t] = b_reflex[t];
    HW[9][t] = w_policy[t];      HW[10][t] = w_policy[Hn + t];
    HW[11][t] = w_motor[t];      HW[12][t] = w_motor[Hn + t];
  }
  if (t < Hn/2){ half2_t z0; z0.x=(_Float16)0.f; z0.y=(_Float16)0.f; hpk[t] = z0; }
  if (t == 0){
    SB[0]=b_gain[0]; SB[1]=b_gain[1];
    SB[2]=b_bias[0]; SB[3]=b_bias[1]; SB[4]=b_bias[2]; SB[5]=b_bias[3];
    SB[6]=b_policy[0]; SB[7]=b_policy[1]; SB[8]=b_motor[0]; SB[9]=b_motor[1];
  }
  float hprev = 0.f;
  __syncthreads();

  const float* xp = x      + (size_t)b * Sn * 6;
  float* rbase    = router + (size_t)b * Sn * Hn;
  const uint4* hv4 = (const uint4*)hpk;

  for (int s = 0; s < Sn; s++){
    // block-uniform x -> SGPRs
    const float x0=rfl_(xp[0]), x1=rfl_(xp[1]), x2=rfl_(xp[2]);
    const float x3=rfl_(xp[3]), x4=rfl_(xp[4]), x5=rfl_(xp[5]);
    half2_t xq0, xq1, xq2;
    xq0.x=(_Float16)x0; xq0.y=(_Float16)x1;
    xq1.x=(_Float16)x2; xq1.y=(_Float16)x3;
    xq2.x=(_Float16)x4; xq2.y=(_Float16)x5;
    // gi = w_ih[t]·x + b_ih[t]
    float gx = fdot2_(wi2, xq2, fdot2_(wi1, xq1, fdot2_(wi0, xq0, bias_i)));

    // gh = w_hh[t]·h + b_hh[t] : 128 dot2, 4 chains
    float a0 = bias_h, a1 = 0.f, a2 = 0.f, a3 = 0.f;
    #pragma unroll
    for (int k = 0; k < 32; k++){
      uint4 hv = hv4[k];            // ds_read_b128, wave-uniform broadcast
      a0 = fdot2_(w[4*k+0], __builtin_bit_cast(half2_t, hv.x), a0);
      a1 = fdot2_(w[4*k+1], __builtin_bit_cast(half2_t, hv.y), a1);
      a2 = fdot2_(w[4*k+2], __builtin_bit_cast(half2_t, hv.z), a2);
      a3 = fdot2_(w[4*k+3], __builtin_bit_cast(half2_t, hv.w), a3);
    }
    float acc = (a0 + a1) + (a2 + a3);
    if (t < 512) A[t] = acc + gx;          // r,z rows: gi+gh fused
    else { A[t] = acc; GIN[t - 512] = gx; } // n rows: keep gi separate
    __syncthreads();                                        // W1

    if (t < Hn){
      float r = sigmoid_(A[t]);
      float z = sigmoid_(A[t + Hn]);
      float n = tanh_(GIN[t] + r * A[t + 2*Hn]);
      float h = (1.f - z) * n + z * hprev;
      hprev = h;
      ((_Float16*)hpk)[t] = (_Float16)h;
      rbase[(size_t)s * Hn + t] = h;                        // router_activity
      float p0=h*HW[0][t], p1=h*HW[1][t], p2=h*HW[2][t];
      float p3=h*HW[3][t], p4=h*HW[4][t], p5=h*HW[5][t];
      #pragma unroll
      for (int off = 32; off >= 1; off >>= 1){
        p0 += __shfl_xor(p0, off); p1 += __shfl_xor(p1, off); p2 += __shfl_xor(p2, off);
        p3 += __shfl_xor(p3, off); p4 += __shfl_xor(p4, off); p5 += __shfl_xor(p5, off);
      }
      if ((t & 63) == 0){
        const int wv = t >> 6;
        REDp[wv][0]=p0; REDp[wv][1]=p1; REDp[wv][2]=p2;
        REDp[wv][3]=p3; REDp[wv][4]=p4; REDp[wv][5]=p5;
      }
    }
    __syncthreads();                                        // W2
    if (t < Hn){
      float g0 = REDp[0][0]+REDp[1][0]+REDp[2][0]+REDp[3][0] + SB[0];
      float g1 = REDp[0][1]+REDp[1][1]+REDp[2][1]+REDp[3][1] + SB[1];
      g0 = sigmoid_(g0); g1 = sigmoid_(g1);
      float f = (x0*g0)*HW[6][t] + (x1*g1)*HW[7][t] + HW[8][t];
      f = fmaxf(f, 0.f);                                    // feat
      float q0=f*HW[9][t], q1=f*HW[10][t], q2=f*HW[11][t], q3=f*HW[12][t];
      #pragma unroll
      for (int off = 32; off >= 1; off >>= 1){
        q0 += __shfl_xor(q0, off); q1 += __shfl_xor(q1, off);
        q2 += __shfl_xor(q2, off); q3 += __shfl_xor(q3, off);
      }
      if ((t & 63) == 0){
        const int wv = t >> 6;
        REDq[wv][0]=q0; REDq[wv][1]=q1; REDq[wv][2]=q2; REDq[wv][3]=q3;
      }
    }
    __syncthreads();                                        // W3
    if (t == 0){
      float s0 = REDq[0][0]+REDq[1][0]+REDq[2][0]+REDq[3][0];
      float s1 = REDq[0][1]+REDq[1][1]+REDq[2][1]+REDq[3][1];
      float s2 = REDq[0][2]+REDq[1][2]+REDq[2][2]+REDq[3][2];
      float s3 = REDq[0][3]+REDq[1][3]+REDq[2][3]+REDq[3][3];
      float B0 = REDp[0][2]+REDp[1][2]+REDp[2][2]+REDp[3][2] + SB[2];
      float B1 = REDp[0][3]+REDp[1][3]+REDp[2][3]+REDp[3][3] + SB[3];
      float B2 = REDp[0][4]+REDp[1][4]+REDp[2][4]+REDp[3][4] + SB[4];
      float B3 = REDp[0][5]+REDp[1][5]+REDp[2][5]+REDp[3][5] + SB[5];
      float4 o;
      o.x = s0 + SB[6] + B0;
      o.y = s1 + SB[7] + B1;
      o.z = tanh_(s2 + SB[8] + B2);
      o.w = tanh_(s3 + SB[9] + B3);
      *(float4*)(y_out + (size_t)b * Sn * 4 + (size_t)s * 4) = o;
    }
    xp += 6;
  }
}

extern "C" void kernel_launch(void* const* d_in, const int* in_sizes, int n_in,
                              void* d_out, int out_size, void* d_ws, size_t ws_size,
                              hipStream_t stream)
{
  const float* x        = (const float*)d_in[0];
  const float* w_ih     = (const float*)d_in[1];
  const float* w_hh     = (const float*)d_in[2];
  const float* b_ih     = (const float*)d_in[3];
  const float* b_hh     = (const float*)d_in[4];
  const float* w_gain   = (const float*)d_in[5];
  const float* b_gain   = (const float*)d_in[6];
  const float* w_bias   = (const float*)d_in[7];
  const float* b_bias   = (const float*)d_in[8];
  const float* w_reflex = (const float*)d_in[9];
  const float* b_reflex = (const float*)d_in[10];
  const float* w_policy = (const float*)d_in[11];
  const float* b_policy = (const float*)d_in[12];
  const float* w_motor  = (const float*)d_in[13];
  const float* b_motor  = (const float*)d_in[14];

  float* y_out  = (float*)d_out;
  float* router = (float*)d_out + (size_t)Bn * Sn * 4;

  bio_rnn<<<dim3(Bn), dim3(NT), 0, stream>>>(
      x, w_ih, w_hh, b_ih, b_hh, w_gain, b_gain, w_bias, b_bias,
      w_reflex, b_reflex, w_policy, b_policy, w_motor, b_motor,
      y_out, router);
}

// Round 7
// 5772.618 us; speedup vs baseline: 1.1541x; 1.1541x over previous
//
#include <hip/hip_runtime.h>
#include <cstdint>
#include <cstddef>

#define Hn 256
#define Sn 2048
#define Bn 128
#define NT 768

typedef _Float16 half2_t __attribute__((ext_vector_type(2)));
typedef _Float16 h16 __attribute__((ext_vector_type(16)));
typedef unsigned int u8v __attribute__((ext_vector_type(8)));

__device__ __forceinline__ half2_t bc2_(unsigned int u){ return __builtin_bit_cast(half2_t, u); }

__device__ __forceinline__ float fdot2_(half2_t a, half2_t b, float c){
#if __has_builtin(__builtin_amdgcn_fdot2)
  return __builtin_amdgcn_fdot2(a, b, c, false);
#else
  float d;
  asm volatile("v_dot2_f32_f16 %0, %1, %2, %3" : "=v"(d) : "v"(a), "v"(b), "v"(c));
  return d;
#endif
}

__device__ __forceinline__ float rfl_(float v){
  return __builtin_bit_cast(float, __builtin_amdgcn_readfirstlane(__builtin_bit_cast(int, v)));
}

__device__ __forceinline__ half2_t pkrtz_(float a, float b){
  return __builtin_bit_cast(half2_t, __builtin_amdgcn_cvt_pkrtz(a, b));
}

__device__ __forceinline__ float sigmoid_(float v){ return 1.0f/(1.0f+__expf(-v)); }
__device__ __forceinline__ float tanh_(float v){
  float e = __expf(-2.0f*__builtin_fabsf(v));
  float r = (1.0f-e)/(1.0f+e);
  return __builtin_copysignf(r, v);
}

// prologue: pack w_hh K[160:256) of each row to f16 dwords in d_ws: [768][48] dwords
__global__ void __launch_bounds__(256)
cvt_ws(const float* __restrict__ w_hh, unsigned int* __restrict__ ws)
{
  int i = blockIdx.x * 256 + threadIdx.x;     // 768*48 = 36864 dwords
  int row = i / 48, c = i % 48;
  float f0 = w_hh[(size_t)row*Hn + 160 + 2*c];
  float f1 = w_hh[(size_t)row*Hn + 160 + 2*c + 1];
  ws[i] = __builtin_bit_cast(unsigned int, pkrtz_(f0, f1));
}

// One workgroup (768 thr = 12 waves) per batch element. Thread t owns w_hh
// row t, split: K[0:80) in 5 v16f16 register groups (40 VGPRs), K[80:160) in
// a 135 KiB LDS slab (staged once), K[160:256) streamed from L2 every step.
// The ~153 KiB LDS caps occupancy at 1 block/CU -> RA budget rises to
// 3 waves/SIMD (rounds 1-5: allocator always targeted 2 blocks/CU and
// spilled any weight array; LDS is the occupancy-limiter that fixes it).
// SM=0: stream f16 from d_ws; SM=1: stream fp32 from w_hh via cvt_pkrtz.
template<int SM>
__global__ void __launch_bounds__(NT)
bio_rnn(const float* __restrict__ x,
        const float* __restrict__ w_ih, const float* __restrict__ w_hh,
        const float* __restrict__ b_ih, const float* __restrict__ b_hh,
        const float* __restrict__ w_gain, const float* __restrict__ b_gain,
        const float* __restrict__ w_bias, const float* __restrict__ b_bias,
        const float* __restrict__ w_reflex, const float* __restrict__ b_reflex,
        const float* __restrict__ w_policy, const float* __restrict__ b_policy,
        const float* __restrict__ w_motor, const float* __restrict__ b_motor,
        const void* __restrict__ wstream,
        float* __restrict__ y_out, float* __restrict__ router)
{
  const int b = blockIdx.x;
  const int t = threadIdx.x;

  __shared__ unsigned int WL[NT * 44];          // K[80:160) f16, 176 B/row stride
  __shared__ __align__(16) half2_t hpk[Hn/2];   // h packed f16
  __shared__ float A[NT];
  __shared__ float GIN[Hn];
  __shared__ float REDp[4][8];
  __shared__ float REDq[4][4];
  __shared__ float HW[13][Hn];
  __shared__ float SB[10];

  // ---- register weights: K[0:80) as 5 x 16-half vectors ----
  h16 W0, W1, W2, W3, W4;
  {
    const float* wr = w_hh + (size_t)t * Hn;
    #pragma unroll
    for (int i = 0; i < 16; i++){
      W0[i] = (_Float16)wr[i];       W1[i] = (_Float16)wr[16+i];
      W2[i] = (_Float16)wr[32+i];    W3[i] = (_Float16)wr[48+i];
      W4[i] = (_Float16)wr[64+i];
    }
    // ---- LDS weights: K[80:160) ----
    #pragma unroll
    for (int i = 0; i < 40; i++){
      WL[t*44 + i] = __builtin_bit_cast(unsigned int, pkrtz_(wr[80+2*i], wr[80+2*i+1]));
    }
  }
  half2_t wi0, wi1, wi2;
  {
    const float* wr = w_ih + (size_t)t * 6;
    wi0 = pkrtz_(wr[0], wr[1]);
    wi1 = pkrtz_(wr[2], wr[3]);
    wi2 = pkrtz_(wr[4], wr[5]);
  }
  const float bias_h = b_hh[t];
  const float bias_i = b_ih[t];

  if (t < Hn){
    HW[0][t] = w_gain[t];        HW[1][t]  = w_gain[Hn + t];
    HW[2][t] = w_bias[t];        HW[3][t]  = w_bias[Hn + t];
    HW[4][t] = w_bias[2*Hn + t]; HW[5][t]  = w_bias[3*Hn + t];
    HW[6][t] = w_reflex[2*t];    HW[7][t]  = w_reflex[2*t + 1];
    HW[8][t] = b_reflex[t];
    HW[9][t] = w_policy[t];      HW[10][t] = w_policy[Hn + t];
    HW[11][t] = w_motor[t];      HW[12][t] = w_motor[Hn + t];
  }
  if (t < Hn/2){ half2_t z0; z0.x=(_Float16)0.f; z0.y=(_Float16)0.f; hpk[t] = z0; }
  if (t == 0){
    SB[0]=b_gain[0]; SB[1]=b_gain[1];
    SB[2]=b_bias[0]; SB[3]=b_bias[1]; SB[4]=b_bias[2]; SB[5]=b_bias[3];
    SB[6]=b_policy[0]; SB[7]=b_policy[1]; SB[8]=b_motor[0]; SB[9]=b_motor[1];
  }
  float hprev = 0.f;
  __syncthreads();

  const float* xp = x      + (size_t)b * Sn * 6;
  float* rbase    = router + (size_t)b * Sn * Hn;
  const uint4* hv4 = (const uint4*)hpk;                 // 32 uint4 = 256 f16
  const uint4* WLv = (const uint4*)WL;                  // row base t*11
  const uint4* S4  = (SM==0) ? ((const uint4*)wstream + (size_t)t*12) : nullptr;
  const float4* SF = (SM==1) ? ((const float4*)wstream + (size_t)t*64 + 40) : nullptr;

#define DOTG(Wg, hb) { u8v wv = __builtin_bit_cast(u8v, Wg);              \
    uint4 ha = hv4[hb], hb2 = hv4[(hb)+1];                                 \
    a0=fdot2_(bc2_(wv[0]),bc2_(ha.x),a0); a1=fdot2_(bc2_(wv[1]),bc2_(ha.y),a1); \
    a2=fdot2_(bc2_(wv[2]),bc2_(ha.z),a2); a3=fdot2_(bc2_(wv[3]),bc2_(ha.w),a3); \
    a0=fdot2_(bc2_(wv[4]),bc2_(hb2.x),a0); a1=fdot2_(bc2_(wv[5]),bc2_(hb2.y),a1); \
    a2=fdot2_(bc2_(wv[6]),bc2_(hb2.z),a2); a3=fdot2_(bc2_(wv[7]),bc2_(hb2.w),a3); }

#define LDOT(c) { uint4 wl = WLv[t*11 + (c)]; uint4 hh = hv4[10 + (c)];    \
    a0=fdot2_(bc2_(wl.x),bc2_(hh.x),a0); a1=fdot2_(bc2_(wl.y),bc2_(hh.y),a1); \
    a2=fdot2_(bc2_(wl.z),bc2_(hh.z),a2); a3=fdot2_(bc2_(wl.w),bc2_(hh.w),a3); }

#define SDOT(sv, c) { uint4 hh = hv4[20 + (c)];                            \
    a0=fdot2_(bc2_(sv.x),bc2_(hh.x),a0); a1=fdot2_(bc2_(sv.y),bc2_(hh.y),a1); \
    a2=fdot2_(bc2_(sv.z),bc2_(hh.z),a2); a3=fdot2_(bc2_(sv.w),bc2_(hh.w),a3); }

#define SDOTF(sa, sb, c) { uint4 hh = hv4[20 + (c)];                       \
    half2_t p0 = pkrtz_(sa.x, sa.y);                                       \
    half2_t p1 = pkrtz_(sa.z, sa.w);                                       \
    half2_t p2 = pkrtz_(sb.x, sb.y);                                       \
    half2_t p3 = pkrtz_(sb.z, sb.w);                                       \
    a0=fdot2_(p0,bc2_(hh.x),a0); a1=fdot2_(p1,bc2_(hh.y),a1);              \
    a2=fdot2_(p2,bc2_(hh.z),a2); a3=fdot2_(p3,bc2_(hh.w),a3); }

  for (int s = 0; s < Sn; s++){
    const float x0=rfl_(xp[0]), x1=rfl_(xp[1]), x2=rfl_(xp[2]);
    const float x3=rfl_(xp[3]), x4=rfl_(xp[4]), x5=rfl_(xp[5]);
    half2_t xq0 = pkrtz_(x0, x1);
    half2_t xq1 = pkrtz_(x2, x3);
    half2_t xq2 = pkrtz_(x4, x5);
    float gx = fdot2_(wi2, xq2, fdot2_(wi1, xq1, fdot2_(wi0, xq0, bias_i)));

    float a0 = bias_h, a1 = 0.f, a2 = 0.f, a3 = 0.f;

    if (SM == 0){
      uint4 s0=S4[0], s1=S4[1], s2=S4[2], s3=S4[3];        // issue early
      DOTG(W0,0); DOTG(W1,2); DOTG(W2,4);
      uint4 s4=S4[4], s5=S4[5], s6=S4[6], s7=S4[7];
      DOTG(W3,6); DOTG(W4,8);
      LDOT(0); LDOT(1); LDOT(2); LDOT(3); LDOT(4);
      uint4 s8=S4[8], s9=S4[9], s10=S4[10], s11=S4[11];
      LDOT(5); LDOT(6); LDOT(7); LDOT(8); LDOT(9);
      SDOT(s0,0); SDOT(s1,1); SDOT(s2,2); SDOT(s3,3);
      SDOT(s4,4); SDOT(s5,5); SDOT(s6,6); SDOT(s7,7);
      SDOT(s8,8); SDOT(s9,9); SDOT(s10,10); SDOT(s11,11);
    } else {
      float4 f0=SF[0], f1=SF[1], f2=SF[2], f3=SF[3];
      DOTG(W0,0); DOTG(W1,2); DOTG(W2,4);
      float4 f4=SF[4], f5=SF[5], f6=SF[6], f7=SF[7];
      DOTG(W3,6); DOTG(W4,8);
      LDOT(0); LDOT(1); LDOT(2); LDOT(3); LDOT(4);
      float4 f8=SF[8], f9=SF[9], f10=SF[10], f11=SF[11];
      LDOT(5); LDOT(6); LDOT(7); LDOT(8); LDOT(9);
      SDOTF(f0,f1,0); SDOTF(f2,f3,1);
      float4 f12=SF[12], f13=SF[13], f14=SF[14], f15=SF[15];
      SDOTF(f4,f5,2); SDOTF(f6,f7,3);
      float4 f16v=SF[16], f17=SF[17], f18=SF[18], f19=SF[19];
      SDOTF(f8,f9,4); SDOTF(f10,f11,5);
      float4 f20=SF[20], f21=SF[21], f22=SF[22], f23=SF[23];
      SDOTF(f12,f13,6); SDOTF(f14,f15,7);
      SDOTF(f16v,f17,8); SDOTF(f18,f19,9);
      SDOTF(f20,f21,10); SDOTF(f22,f23,11);
    }

    float acc = (a0 + a1) + (a2 + a3);
    if (t < 512) A[t] = acc + gx;
    else { A[t] = acc; GIN[t - 512] = gx; }
    __syncthreads();                                        // W1

    if (t < Hn){
      float r = sigmoid_(A[t]);
      float z = sigmoid_(A[t + Hn]);
      float n = tanh_(GIN[t] + r * A[t + 2*Hn]);
      float h = (1.f - z) * n + z * hprev;
      hprev = h;
      ((_Float16*)hpk)[t] = (_Float16)h;
      rbase[(size_t)s * Hn + t] = h;
      float p0=h*HW[0][t], p1=h*HW[1][t], p2=h*HW[2][t];
      float p3=h*HW[3][t], p4=h*HW[4][t], p5=h*HW[5][t];
      #pragma unroll
      for (int off = 32; off >= 1; off >>= 1){
        p0 += __shfl_xor(p0, off); p1 += __shfl_xor(p1, off); p2 += __shfl_xor(p2, off);
        p3 += __shfl_xor(p3, off); p4 += __shfl_xor(p4, off); p5 += __shfl_xor(p5, off);
      }
      if ((t & 63) == 0){
        const int wv = t >> 6;
        REDp[wv][0]=p0; REDp[wv][1]=p1; REDp[wv][2]=p2;
        REDp[wv][3]=p3; REDp[wv][4]=p4; REDp[wv][5]=p5;
      }
    }
    __syncthreads();                                        // W2
    if (t < Hn){
      float g0 = REDp[0][0]+REDp[1][0]+REDp[2][0]+REDp[3][0] + SB[0];
      float g1 = REDp[0][1]+REDp[1][1]+REDp[2][1]+REDp[3][1] + SB[1];
      g0 = sigmoid_(g0); g1 = sigmoid_(g1);
      float f = (x0*g0)*HW[6][t] + (x1*g1)*HW[7][t] + HW[8][t];
      f = fmaxf(f, 0.f);
      float q0=f*HW[9][t], q1=f*HW[10][t], q2=f*HW[11][t], q3=f*HW[12][t];
      #pragma unroll
      for (int off = 32; off >= 1; off >>= 1){
        q0 += __shfl_xor(q0, off); q1 += __shfl_xor(q1, off);
        q2 += __shfl_xor(q2, off); q3 += __shfl_xor(q3, off);
      }
      if ((t & 63) == 0){
        const int wv = t >> 6;
        REDq[wv][0]=q0; REDq[wv][1]=q1; REDq[wv][2]=q2; REDq[wv][3]=q3;
      }
    }
    __syncthreads();                                        // W3
    if (t == 0){
      float s0 = REDq[0][0]+REDq[1][0]+REDq[2][0]+REDq[3][0];
      float s1 = REDq[0][1]+REDq[1][1]+REDq[2][1]+REDq[3][1];
      float s2 = REDq[0][2]+REDq[1][2]+REDq[2][2]+REDq[3][2];
      float s3 = REDq[0][3]+REDq[1][3]+REDq[2][3]+REDq[3][3];
      float B0 = REDp[0][2]+REDp[1][2]+REDp[2][2]+REDp[3][2] + SB[2];
      float B1 = REDp[0][3]+REDp[1][3]+REDp[2][3]+REDp[3][3] + SB[3];
      float B2 = REDp[0][4]+REDp[1][4]+REDp[2][4]+REDp[3][4] + SB[4];
      float B3 = REDp[0][5]+REDp[1][5]+REDp[2][5]+REDp[3][5] + SB[5];
      float4 o;
      o.x = s0 + SB[6] + B0;
      o.y = s1 + SB[7] + B1;
      o.z = tanh_(s2 + SB[8] + B2);
      o.w = tanh_(s3 + SB[9] + B3);
      *(float4*)(y_out + (size_t)b * Sn * 4 + (size_t)s * 4) = o;
    }
    xp += 6;
  }
#undef DOTG
#undef LDOT
#undef SDOT
#undef SDOTF
}

extern "C" void kernel_launch(void* const* d_in, const int* in_sizes, int n_in,
                              void* d_out, int out_size, void* d_ws, size_t ws_size,
                              hipStream_t stream)
{
  const float* x        = (const float*)d_in[0];
  const float* w_ih     = (const float*)d_in[1];
  const float* w_hh     = (const float*)d_in[2];
  const float* b_ih     = (const float*)d_in[3];
  const float* b_hh     = (const float*)d_in[4];
  const float* w_gain   = (const float*)d_in[5];
  const float* b_gain   = (const float*)d_in[6];
  const float* w_bias   = (const float*)d_in[7];
  const float* b_bias   = (const float*)d_in[8];
  const float* w_reflex = (const float*)d_in[9];
  const float* b_reflex = (const float*)d_in[10];
  const float* w_policy = (const float*)d_in[11];
  const float* b_policy = (const float*)d_in[12];
  const float* w_motor  = (const float*)d_in[13];
  const float* b_motor  = (const float*)d_in[14];

  float* y_out  = (float*)d_out;
  float* router = (float*)d_out + (size_t)Bn * Sn * 4;

  const size_t ws_need = (size_t)NT * 48 * 4;   // 147456 B f16 stream copy
  if (ws_size >= ws_need){
    cvt_ws<<<dim3(144), dim3(256), 0, stream>>>(w_hh, (unsigned int*)d_ws);
    bio_rnn<0><<<dim3(Bn), dim3(NT), 0, stream>>>(
        x, w_ih, w_hh, b_ih, b_hh, w_gain, b_gain, w_bias, b_bias,
        w_reflex, b_reflex, w_policy, b_policy, w_motor, b_motor,
        (const void*)d_ws, y_out, router);
  } else {
    bio_rnn<1><<<dim3(Bn), dim3(NT), 0, stream>>>(
        x, w_ih, w_hh, b_ih, b_hh, w_gain, b_gain, w_bias, b_bias,
        w_reflex, b_reflex, w_policy, b_policy, w_motor, b_motor,
        (const void*)w_hh, y_out, router);
  }
}